// Round 3
// baseline (602.612 us; speedup 1.0000x reference)
//
#include <hip/hip_runtime.h>
#include <cmath>

// ---------- bf16 pack/unpack (packed pairs in unsigned) ----------
static __device__ __forceinline__ unsigned short f2bf(float f) {
    unsigned u = __float_as_uint(f);
    unsigned r = (u + 0x7fffu + ((u >> 16) & 1u)) >> 16;   // RNE
    return (unsigned short)r;
}
static __device__ __forceinline__ float bflo(unsigned u) { return __uint_as_float(u << 16); }
static __device__ __forceinline__ float bfhi(unsigned u) { return __uint_as_float(u & 0xffff0000u); }

// ---------- fills ----------
__global__ void fill_i32_k(int* __restrict__ p, size_t n, int v) {
    size_t i = (size_t)blockIdx.x * blockDim.x + threadIdx.x;
    if (i < n) p[i] = v;
}

// ---------- CSR build ----------
__global__ void count_k(const int* __restrict__ dst, int E, int* __restrict__ deg) {
    int e = blockIdx.x * blockDim.x + threadIdx.x;
    if (e < E) atomicAdd(&deg[dst[e]], 1);
}

#define SCAN_BLK 256
#define SCAN_ELEMS 2048   // 8 per thread

__global__ void scan1_k(const int* __restrict__ deg, int* __restrict__ rowstart,
                        int* __restrict__ bsums, int N) {
    __shared__ int sh[SCAN_BLK];
    int t = threadIdx.x;
    int base = blockIdx.x * SCAN_ELEMS + t * 8;
    int vals[8];
    int sum = 0;
#pragma unroll
    for (int i = 0; i < 8; ++i) {
        int idx = base + i;
        vals[i] = (idx < N) ? deg[idx] : 0;
        sum += vals[i];
    }
    sh[t] = sum;
    __syncthreads();
    for (int off = 1; off < SCAN_BLK; off <<= 1) {
        int v = (t >= off) ? sh[t - off] : 0;
        __syncthreads();
        sh[t] += v;
        __syncthreads();
    }
    int run = sh[t] - sum;
    if (t == SCAN_BLK - 1) bsums[blockIdx.x] = sh[t];
#pragma unroll
    for (int i = 0; i < 8; ++i) {
        int idx = base + i;
        if (idx < N) rowstart[idx] = run;
        run += vals[i];
    }
}

__global__ void scan2_k(int* __restrict__ bsums, int nb) {
    if (threadIdx.x == 0 && blockIdx.x == 0) {
        int run = 0;
        for (int i = 0; i < nb; ++i) { int t = bsums[i]; bsums[i] = run; run += t; }
    }
}

__global__ void scan3_k(int* __restrict__ rowstart, const int* __restrict__ bsums, int N, int total) {
    int i = blockIdx.x * blockDim.x + threadIdx.x;
    if (i < N) rowstart[i] += bsums[i / SCAN_ELEMS];
    else if (i == N) rowstart[N] = total;
}

__global__ void initadj_k(const int* __restrict__ rowstart, int* __restrict__ adj,
                          int* __restrict__ cursor, int N) {
    int n = blockIdx.x * blockDim.x + threadIdx.x;
    if (n >= N) return;
    int r = rowstart[n];
    adj[r] = n;          // self-loop first
    cursor[n] = r + 1;
}

__global__ void scatter_k(const int* __restrict__ src, const int* __restrict__ dst, int E,
                          int* __restrict__ cursor, int* __restrict__ adj) {
    int e = blockIdx.x * blockDim.x + threadIdx.x;
    if (e >= E) return;
    int pos = atomicAdd(&cursor[dst[e]], 1);
    adj[pos] = src[e];
}

// ---------- GEMM: Y = X[N,K] @ W[K,NOUT]; NOUT threads/block, R rows/block ----------
// X is read with block-uniform indices -> scalar (s_load) broadcasts, no LDS.
// Also emits packed-bf16 copy Yb for the gather kernel.
template<int K, int NOUT, int R>
__global__ void gemm_rows_k(const float* __restrict__ X, const float* __restrict__ W,
                            float* __restrict__ Y, unsigned short* __restrict__ Yb, int N) {
    int c = threadIdx.x;
    int n0 = blockIdx.x * R;
    int rmax = (N - n0 < R) ? (N - n0) : R;
    const float* Wp = W + c;
    const float* Xp = X + (size_t)n0 * K;
    float acc[R];
#pragma unroll
    for (int r = 0; r < R; ++r) acc[r] = 0.f;
    for (int k = 0; k < K; k += 4) {
        float w0 = Wp[(size_t)k * NOUT];
        float w1 = Wp[(size_t)(k + 1) * NOUT];
        float w2 = Wp[(size_t)(k + 2) * NOUT];
        float w3 = Wp[(size_t)(k + 3) * NOUT];
#pragma unroll
        for (int r = 0; r < R; ++r) {
            int rr = (r < rmax) ? r : 0;           // clamp (no tail at these sizes)
            const float* xr = Xp + (size_t)rr * K + k;
            acc[r] = fmaf(xr[0], w0, acc[r]);
            acc[r] = fmaf(xr[1], w1, acc[r]);
            acc[r] = fmaf(xr[2], w2, acc[r]);
            acc[r] = fmaf(xr[3], w3, acc[r]);
        }
    }
#pragma unroll
    for (int r = 0; r < R; ++r) {
        if (r < rmax) {
            Y[(size_t)(n0 + r) * NOUT + c] = acc[r];
            Yb[(size_t)(n0 + r) * NOUT + c] = f2bf(acc[r]);
        }
    }
}

// ---------- attention scores ----------
template<int H, int C>
__global__ void score_k(const float* __restrict__ h, const float* __restrict__ a_src,
                        const float* __restrict__ a_dst,
                        float* __restrict__ s_src, float* __restrict__ s_dst, int N) {
    int idx = blockIdx.x * blockDim.x + threadIdx.x;
    if (idx >= N * H) return;
    int n = idx / H, hh = idx % H;
    const float4* hp = reinterpret_cast<const float4*>(h + (size_t)n * H * C + (size_t)hh * C);
    const float4* as = reinterpret_cast<const float4*>(a_src + hh * C);
    const float4* ad = reinterpret_cast<const float4*>(a_dst + hh * C);
    float ss = 0.f, sd = 0.f;
#pragma unroll 4
    for (int c = 0; c < C / 4; ++c) {
        float4 v = hp[c], a = as[c], d = ad[c];
        ss += v.x * a.x + v.y * a.y + v.z * a.z + v.w * a.w;
        sd += v.x * d.x + v.y * d.y + v.z * d.z + v.w * d.w;
    }
    s_src[idx] = ss;
    s_dst[idx] = sd;
}

// ---------- fused per-node softmax + bf16 gather-aggregate + bias(+ELU) ----------
// one 64-lane wave per destination node; 4 waves per block
template<int H, int C, bool ELU>
__global__ void node_agg_k(const int* __restrict__ rowstart, const int* __restrict__ adj,
                           const float* __restrict__ ssrc, const float* __restrict__ sdst,
                           const unsigned* __restrict__ hb, const float* __restrict__ bias,
                           float* __restrict__ out, int N) {
    constexpr int HC = H * C;
    constexpr int FPL = HC / 64;            // features per lane (4 or 2)
    constexpr int UPL = FPL / 2;            // packed uints per lane (2 or 1)
    int lane = threadIdx.x & 63;
    int n = blockIdx.x * (blockDim.x >> 6) + (threadIdx.x >> 6);
    if (n >= N) return;
    int r0 = rowstart[n], r1 = rowstart[n + 1];

    float sd[H], m[H], l[H];
#pragma unroll
    for (int h = 0; h < H; ++h) { sd[h] = sdst[n * H + h]; m[h] = -1e30f; l[h] = 0.f; }

    // pass 1: online softmax stats, lanes strided over edges
    for (int e = r0 + lane; e < r1; e += 64) {
        int s = adj[e];
        if constexpr (H == 4) {
            float4 sv = reinterpret_cast<const float4*>(ssrc)[s];
            float vv[4] = {sv.x, sv.y, sv.z, sv.w};
#pragma unroll
            for (int h = 0; h < 4; ++h) {
                float v = vv[h] + sd[h];
                v = v > 0.f ? v : 0.2f * v;
                float mn = fmaxf(m[h], v);
                l[h] = l[h] * __expf(m[h] - mn) + __expf(v - mn);
                m[h] = mn;
            }
        } else {
            float v = ssrc[s] + sd[0];
            v = v > 0.f ? v : 0.2f * v;
            float mn = fmaxf(m[0], v);
            l[0] = l[0] * __expf(m[0] - mn) + __expf(v - mn);
            m[0] = mn;
        }
    }
    // wave-wide combine of (m, l)
#pragma unroll
    for (int off = 32; off; off >>= 1) {
#pragma unroll
        for (int h = 0; h < H; ++h) {
            float mo = __shfl_xor(m[h], off, 64);
            float lo = __shfl_xor(l[h], off, 64);
            float mn = fmaxf(m[h], mo);
            l[h] = l[h] * __expf(m[h] - mn) + lo * __expf(mo - mn);
            m[h] = mn;
        }
    }

    // pass 2: gather-weighted aggregation over packed-bf16 rows
    int hA = (lane * FPL) / C;
    float mh = m[hA], invl = 1.f / l[hA], sdh = sd[hA];
    float acc[FPL];
#pragma unroll
    for (int f = 0; f < FPL; ++f) acc[f] = 0.f;

    auto body = [&](int s) {
        float v = ssrc[s * H + hA] + sdh;
        v = v > 0.f ? v : 0.2f * v;
        float alpha = __expf(v - mh) * invl;
        const unsigned* hp = hb + (size_t)s * (HC / 2) + lane * UPL;
        if constexpr (UPL == 2) {
            uint2 u = *reinterpret_cast<const uint2*>(hp);
            acc[0] += alpha * bflo(u.x); acc[1] += alpha * bfhi(u.x);
            acc[2] += alpha * bflo(u.y); acc[3] += alpha * bfhi(u.y);
        } else {
            unsigned u = *hp;
            acc[0] += alpha * bflo(u); acc[1] += alpha * bfhi(u);
        }
    };
    int e = r0;
    for (; e + 1 < r1; e += 2) { int s0 = adj[e], s1 = adj[e + 1]; body(s0); body(s1); }
    if (e < r1) body(adj[e]);

    float* op = out + (size_t)n * HC + lane * FPL;
#pragma unroll
    for (int f = 0; f < FPL; ++f) {
        float v = acc[f] + bias[lane * FPL + f];
        if (ELU) v = v > 0.f ? v : (__expf(v) - 1.f);
        op[f] = v;
    }
}

// ---------- launch ----------
extern "C" void kernel_launch(void* const* d_in, const int* in_sizes, int n_in,
                              void* d_out, int out_size, void* d_ws, size_t ws_size,
                              hipStream_t stream) {
    const float* x   = (const float*)d_in[0];
    const int*   ei  = (const int*)d_in[1];
    const float* W1  = (const float*)d_in[2];
    const float* as1 = (const float*)d_in[3];
    const float* ad1 = (const float*)d_in[4];
    const float* b1  = (const float*)d_in[5];
    const float* W2  = (const float*)d_in[6];
    const float* as2 = (const float*)d_in[7];
    const float* ad2 = (const float*)d_in[8];
    const float* b2  = (const float*)d_in[9];
    float* out = (float*)d_out;

    const int N  = in_sizes[0] / 128;   // 50000
    const int E  = in_sizes[1] / 2;     // 800000
    const int ET = E + N;
    const int* src = ei;
    const int* dst = ei + E;

    // workspace layout (4B units)
    float* ws = (float*)d_ws;
    float*    h1    = ws;                              // N*256 f32
    float*    agg1  = h1    + (size_t)N * 256;         // N*256 f32
    unsigned* h1b   = (unsigned*)(agg1 + (size_t)N * 256); // N*128 packed bf16 (reused as h2b N*64)
    float*    ssrc1 = (float*)(h1b + (size_t)N * 128); // N*4
    float*    sdst1 = ssrc1 + (size_t)N * 4;           // N*4
    float*    ssrc2 = sdst1 + (size_t)N * 4;           // N
    float*    sdst2 = ssrc2 + N;                       // N
    int*      deg   = (int*)(sdst2 + N);               // N (reused as cursor)
    int*      rowst = deg + N;                         // N+1
    int*      bsums = rowst + N + 1;                   // 64
    int*      adj   = bsums + 64;                      // ET
    float*    h2    = h1;                              // layer-2 features f32 [N,128]
    unsigned* h2b   = h1b;                             // layer-2 packed bf16 [N,64]

    const int B = 256;
    auto blocks = [](size_t n, int b) { return (int)((n + b - 1) / b); };
    const int nscan = (N + SCAN_ELEMS - 1) / SCAN_ELEMS;

    // ---- CSR build (shared by both layers) ----
    fill_i32_k<<<blocks(N, B), B, 0, stream>>>(deg, N, 1);          // self-loop
    count_k<<<blocks(E, B), B, 0, stream>>>(dst, E, deg);
    scan1_k<<<nscan, SCAN_BLK, 0, stream>>>(deg, rowst, bsums, N);
    scan2_k<<<1, 64, 0, stream>>>(bsums, nscan);
    scan3_k<<<blocks(N + 1, B), B, 0, stream>>>(rowst, bsums, N, ET);
    initadj_k<<<blocks(N, B), B, 0, stream>>>(rowst, adj, deg, N);  // deg becomes cursor
    scatter_k<<<blocks(E, B), B, 0, stream>>>(src, dst, E, deg, adj);

    // ---- layer 1 ----
    gemm_rows_k<128, 256, 16><<<(N + 15) / 16, 256, 0, stream>>>(x, W1, h1, (unsigned short*)h1b, N);
    score_k<4, 64><<<blocks((size_t)N * 4, B), B, 0, stream>>>(h1, as1, ad1, ssrc1, sdst1, N);
    node_agg_k<4, 64, true><<<(N + 3) / 4, 256, 0, stream>>>(rowst, adj, ssrc1, sdst1, h1b, b1, agg1, N);

    // ---- layer 2 ----
    gemm_rows_k<256, 128, 16><<<(N + 15) / 16, 128, 0, stream>>>(agg1, W2, h2, (unsigned short*)h2b, N);
    score_k<1, 128><<<blocks(N, B), B, 0, stream>>>(h2, as2, ad2, ssrc2, sdst2, N);
    node_agg_k<1, 128, false><<<(N + 3) / 4, 256, 0, stream>>>(rowst, adj, ssrc2, sdst2, h2b, b2, out, N);
}

// Round 4
// 331.024 us; speedup vs baseline: 1.8204x; 1.8204x over previous
//
#include <hip/hip_runtime.h>
#include <cmath>

typedef __attribute__((ext_vector_type(8))) short bf16x8;
typedef __attribute__((ext_vector_type(4))) float f32x4;

// ---------- bf16 pack/unpack ----------
static __device__ __forceinline__ unsigned short f2bf(float f) {
    unsigned u = __float_as_uint(f);
    unsigned r = (u + 0x7fffu + ((u >> 16) & 1u)) >> 16;   // RNE
    return (unsigned short)r;
}
static __device__ __forceinline__ unsigned packbf(float a, float b) {
    return (unsigned)f2bf(a) | ((unsigned)f2bf(b) << 16);
}
static __device__ __forceinline__ float bflo(unsigned u) { return __uint_as_float(u << 16); }
static __device__ __forceinline__ float bfhi(unsigned u) { return __uint_as_float(u & 0xffff0000u); }

// ---------- fills / converts ----------
__global__ void fill_i32_k(int* __restrict__ p, size_t n, int v) {
    size_t i = (size_t)blockIdx.x * blockDim.x + threadIdx.x;
    if (i < n) p[i] = v;
}
__global__ void cvt_pack_k(const float* __restrict__ X, unsigned* __restrict__ Xb, size_t n2) {
    size_t i = (size_t)blockIdx.x * blockDim.x + threadIdx.x;
    if (i >= n2) return;
    float2 v = reinterpret_cast<const float2*>(X)[i];
    Xb[i] = packbf(v.x, v.y);
}
template<int K, int NOUT>
__global__ void wcvt_k(const float* __restrict__ W, unsigned short* __restrict__ Wt) {
    int i = blockIdx.x * blockDim.x + threadIdx.x;   // over K*NOUT, n-major
    if (i >= K * NOUT) return;
    int n = i / K, k = i % K;
    Wt[i] = f2bf(W[(size_t)k * NOUT + n]);
}

// ---------- CSR build ----------
__global__ void count_k(const int* __restrict__ dst, int E, int* __restrict__ deg) {
    int e = blockIdx.x * blockDim.x + threadIdx.x;
    if (e < E) atomicAdd(&deg[dst[e]], 1);
}

#define SCAN_BLK 256
#define SCAN_ELEMS 2048

__global__ void scan1_k(const int* __restrict__ deg, int* __restrict__ rowstart,
                        int* __restrict__ bsums, int N) {
    __shared__ int sh[SCAN_BLK];
    int t = threadIdx.x;
    int base = blockIdx.x * SCAN_ELEMS + t * 8;
    int vals[8];
    int sum = 0;
#pragma unroll
    for (int i = 0; i < 8; ++i) {
        int idx = base + i;
        vals[i] = (idx < N) ? deg[idx] : 0;
        sum += vals[i];
    }
    sh[t] = sum;
    __syncthreads();
    for (int off = 1; off < SCAN_BLK; off <<= 1) {
        int v = (t >= off) ? sh[t - off] : 0;
        __syncthreads();
        sh[t] += v;
        __syncthreads();
    }
    int run = sh[t] - sum;
    if (t == SCAN_BLK - 1) bsums[blockIdx.x] = sh[t];
#pragma unroll
    for (int i = 0; i < 8; ++i) {
        int idx = base + i;
        if (idx < N) rowstart[idx] = run;
        run += vals[i];
    }
}
__global__ void scan2_k(int* __restrict__ bsums, int nb) {
    if (threadIdx.x == 0 && blockIdx.x == 0) {
        int run = 0;
        for (int i = 0; i < nb; ++i) { int t = bsums[i]; bsums[i] = run; run += t; }
    }
}
__global__ void scan3_k(int* __restrict__ rowstart, const int* __restrict__ bsums, int N, int total) {
    int i = blockIdx.x * blockDim.x + threadIdx.x;
    if (i < N) rowstart[i] += bsums[i / SCAN_ELEMS];
    else if (i == N) rowstart[N] = total;
}
__global__ void initadj_k(const int* __restrict__ rowstart, int* __restrict__ adj,
                          int* __restrict__ cursor, int N) {
    int n = blockIdx.x * blockDim.x + threadIdx.x;
    if (n >= N) return;
    int r = rowstart[n];
    adj[r] = n;
    cursor[n] = r + 1;
}
__global__ void scatter_k(const int* __restrict__ src, const int* __restrict__ dst, int E,
                          int* __restrict__ cursor, int* __restrict__ adj) {
    int e = blockIdx.x * blockDim.x + threadIdx.x;
    if (e >= E) return;
    int pos = atomicAdd(&cursor[dst[e]], 1);
    adj[pos] = src[e];
}

// ---------- MFMA GEMM: Yb[N,NOUT](bf16) = Ab[N,K](bf16) @ Wt[NOUT,K](bf16)^T ----------
// BM=128, BN=64, BK=64; 256 threads = 4 waves (2x2); XOR-swizzled LDS (T2).
template<int K, int NOUT>
__global__ __launch_bounds__(256) void gemm_mfma_k(const unsigned* __restrict__ Ab,
                                                   const unsigned* __restrict__ Bt,
                                                   unsigned short* __restrict__ Yb, int N) {
    __shared__ unsigned short As[128 * 64];
    __shared__ unsigned short Bs[64 * 64];
    int tid = threadIdx.x;
    int lane = tid & 63, wid = tid >> 6;
    int wm = wid >> 1, wc = wid & 1;
    int m0 = blockIdx.x * 128;
    int n0 = blockIdx.y * 64;

    f32x4 acc[4][2] = {};

    for (int k0 = 0; k0 < K; k0 += 64) {
        // stage A: 128 rows x 64 bf16 -> 1024 16B-granules, 4 passes
#pragma unroll
        for (int p = 0; p < 4; ++p) {
            int gl = p * 256 + tid;
            int row = gl >> 3, g = gl & 7;
            int grow = m0 + row; if (grow >= N) grow = N - 1;
            uint4 v = *reinterpret_cast<const uint4*>(Ab + (size_t)grow * (K / 2) + k0 / 2 + g * 4);
            *reinterpret_cast<uint4*>((char*)As + row * 128 + ((g ^ (row & 7)) << 4)) = v;
        }
        // stage B: 64 rows(out-cols) x 64 bf16 -> 512 granules, 2 passes
#pragma unroll
        for (int p = 0; p < 2; ++p) {
            int gl = p * 256 + tid;
            int row = gl >> 3, g = gl & 7;
            uint4 v = *reinterpret_cast<const uint4*>(Bt + (size_t)(n0 + row) * (K / 2) + k0 / 2 + g * 4);
            *reinterpret_cast<uint4*>((char*)Bs + row * 128 + ((g ^ (row & 7)) << 4)) = v;
        }
        __syncthreads();

        bf16x8 bfrag[2][2];
#pragma unroll
        for (int kk = 0; kk < 2; ++kk)
#pragma unroll
            for (int no = 0; no < 2; ++no) {
                int row = wc * 32 + no * 16 + (lane & 15);
                int g = kk * 4 + (lane >> 4);
                bfrag[kk][no] = *reinterpret_cast<const bf16x8*>((char*)Bs + row * 128 + ((g ^ (row & 7)) << 4));
            }
#pragma unroll
        for (int mo = 0; mo < 4; ++mo) {
#pragma unroll
            for (int kk = 0; kk < 2; ++kk) {
                int row = wm * 64 + mo * 16 + (lane & 15);
                int g = kk * 4 + (lane >> 4);
                bf16x8 afrag = *reinterpret_cast<const bf16x8*>((char*)As + row * 128 + ((g ^ (row & 7)) << 4));
                acc[mo][0] = __builtin_amdgcn_mfma_f32_16x16x32_bf16(afrag, bfrag[kk][0], acc[mo][0], 0, 0, 0);
                acc[mo][1] = __builtin_amdgcn_mfma_f32_16x16x32_bf16(afrag, bfrag[kk][1], acc[mo][1], 0, 0, 0);
            }
        }
        __syncthreads();
    }
    // epilogue: bf16 store
#pragma unroll
    for (int mo = 0; mo < 4; ++mo)
#pragma unroll
        for (int no = 0; no < 2; ++no) {
            int col = n0 + wc * 32 + no * 16 + (lane & 15);
            int rbase = m0 + wm * 64 + mo * 16 + (lane >> 4) * 4;
#pragma unroll
            for (int j = 0; j < 4; ++j) {
                int row = rbase + j;
                if (row < N) Yb[(size_t)row * NOUT + col] = f2bf(acc[mo][no][j]);
            }
        }
}

// ---------- attention scores from packed-bf16 features ----------
template<int H, int C>
__global__ void score_b_k(const unsigned* __restrict__ hb, const float* __restrict__ a_src,
                          const float* __restrict__ a_dst,
                          float* __restrict__ ssrc, float* __restrict__ sdst, int N) {
    int idx = blockIdx.x * blockDim.x + threadIdx.x;
    if (idx >= N * H) return;
    int n = idx / H, hh = idx % H;
    const uint4* hp = reinterpret_cast<const uint4*>(hb + (size_t)n * (H * C / 2) + hh * (C / 2));
    const float* as = a_src + hh * C;
    const float* ad = a_dst + hh * C;
    float ss = 0.f, sd = 0.f;
#pragma unroll
    for (int i = 0; i < C / 8; ++i) {
        uint4 u = hp[i];
        float v[8] = {bflo(u.x), bfhi(u.x), bflo(u.y), bfhi(u.y),
                      bflo(u.z), bfhi(u.z), bflo(u.w), bfhi(u.w)};
#pragma unroll
        for (int j = 0; j < 8; ++j) { ss += v[j] * as[i * 8 + j]; sd += v[j] * ad[i * 8 + j]; }
    }
    ssrc[idx] = ss;
    sdst[idx] = sd;
}

// ---------- fused per-node softmax + bf16 gather-aggregate + epilogue ----------
// OUT_BF16: write packed bf16 (layer1 -> gemm2 input), else f32.
template<int H, int C, bool ELU, bool OUT_BF16>
__global__ void node_agg_k(const int* __restrict__ rowstart, const int* __restrict__ adj,
                           const float* __restrict__ ssrc, const float* __restrict__ sdst,
                           const unsigned* __restrict__ hb, const float* __restrict__ bias,
                           void* __restrict__ outp, int N) {
    constexpr int HC = H * C;
    constexpr int FPL = HC / 64;            // 4 or 2
    constexpr int UPL = FPL / 2;            // 2 or 1
    int lane = threadIdx.x & 63;
    int n = blockIdx.x * (blockDim.x >> 6) + (threadIdx.x >> 6);
    if (n >= N) return;
    int r0 = rowstart[n], r1 = rowstart[n + 1];

    float sd[H], m[H], l[H];
#pragma unroll
    for (int h = 0; h < H; ++h) { sd[h] = sdst[n * H + h]; m[h] = -1e30f; l[h] = 0.f; }

    for (int e = r0 + lane; e < r1; e += 64) {
        int s = adj[e];
        if constexpr (H == 4) {
            float4 sv = reinterpret_cast<const float4*>(ssrc)[s];
            float vv[4] = {sv.x, sv.y, sv.z, sv.w};
#pragma unroll
            for (int h = 0; h < 4; ++h) {
                float v = vv[h] + sd[h];
                v = v > 0.f ? v : 0.2f * v;
                float mn = fmaxf(m[h], v);
                l[h] = l[h] * __expf(m[h] - mn) + __expf(v - mn);
                m[h] = mn;
            }
        } else {
            float v = ssrc[s] + sd[0];
            v = v > 0.f ? v : 0.2f * v;
            float mn = fmaxf(m[0], v);
            l[0] = l[0] * __expf(m[0] - mn) + __expf(v - mn);
            m[0] = mn;
        }
    }
#pragma unroll
    for (int off = 32; off; off >>= 1) {
#pragma unroll
        for (int h = 0; h < H; ++h) {
            float mo = __shfl_xor(m[h], off, 64);
            float lo = __shfl_xor(l[h], off, 64);
            float mn = fmaxf(m[h], mo);
            l[h] = l[h] * __expf(m[h] - mn) + lo * __expf(mo - mn);
            m[h] = mn;
        }
    }

    int hA = (lane * FPL) / C;
    float mh = m[hA], invl = 1.f / l[hA], sdh = sd[hA];
    float acc[FPL];
#pragma unroll
    for (int f = 0; f < FPL; ++f) acc[f] = 0.f;

    auto body = [&](int s) {
        float v = ssrc[s * H + hA] + sdh;
        v = v > 0.f ? v : 0.2f * v;
        float alpha = __expf(v - mh) * invl;
        const unsigned* hp = hb + (size_t)s * (HC / 2) + lane * UPL;
        if constexpr (UPL == 2) {
            uint2 u = *reinterpret_cast<const uint2*>(hp);
            acc[0] += alpha * bflo(u.x); acc[1] += alpha * bfhi(u.x);
            acc[2] += alpha * bflo(u.y); acc[3] += alpha * bfhi(u.y);
        } else {
            unsigned u = *hp;
            acc[0] += alpha * bflo(u); acc[1] += alpha * bfhi(u);
        }
    };
    int e = r0;
    for (; e + 1 < r1; e += 2) { int s0 = adj[e], s1 = adj[e + 1]; body(s0); body(s1); }
    if (e < r1) body(adj[e]);

#pragma unroll
    for (int f = 0; f < FPL; ++f) {
        float v = acc[f] + bias[lane * FPL + f];
        if (ELU) v = v > 0.f ? v : (__expf(v) - 1.f);
        acc[f] = v;
    }
    if constexpr (OUT_BF16) {
        unsigned* op = (unsigned*)outp + (size_t)n * (HC / 2) + lane * UPL;
        if constexpr (UPL == 2) {
            uint2 u = {packbf(acc[0], acc[1]), packbf(acc[2], acc[3])};
            *reinterpret_cast<uint2*>(op) = u;
        } else {
            *op = packbf(acc[0], acc[1]);
        }
    } else {
        float* op = (float*)outp + (size_t)n * HC + lane * FPL;
        if constexpr (FPL == 2) {
            *reinterpret_cast<float2*>(op) = make_float2(acc[0], acc[1]);
        } else {
#pragma unroll
            for (int f = 0; f < FPL; ++f) op[f] = acc[f];
        }
    }
}

// ---------- launch ----------
extern "C" void kernel_launch(void* const* d_in, const int* in_sizes, int n_in,
                              void* d_out, int out_size, void* d_ws, size_t ws_size,
                              hipStream_t stream) {
    const float* x   = (const float*)d_in[0];
    const int*   ei  = (const int*)d_in[1];
    const float* W1  = (const float*)d_in[2];
    const float* as1 = (const float*)d_in[3];
    const float* ad1 = (const float*)d_in[4];
    const float* b1  = (const float*)d_in[5];
    const float* W2  = (const float*)d_in[6];
    const float* as2 = (const float*)d_in[7];
    const float* ad2 = (const float*)d_in[8];
    const float* b2  = (const float*)d_in[9];
    float* out = (float*)d_out;

    const int N  = in_sizes[0] / 128;   // 50000
    const int E  = in_sizes[1] / 2;     // 800000
    const int ET = E + N;
    const int* src = ei;
    const int* dst = ei + E;

    // workspace (4B units)
    unsigned* ws = (unsigned*)d_ws;
    unsigned* xb    = ws;                              // N*64  (x bf16)
    unsigned* h1b   = xb    + (size_t)N * 64;          // N*128
    unsigned* agg1b = h1b   + (size_t)N * 128;         // N*128
    unsigned* h2b   = agg1b + (size_t)N * 128;         // N*64
    unsigned* Wt1   = h2b   + (size_t)N * 64;          // 128*256/2 = 16384
    unsigned* Wt2   = Wt1   + 16384;                   // 16384
    float*    ssrc1 = (float*)(Wt2 + 16384);           // N*4
    float*    sdst1 = ssrc1 + (size_t)N * 4;           // N*4
    float*    ssrc2 = sdst1 + (size_t)N * 4;           // N
    float*    sdst2 = ssrc2 + N;                       // N
    int*      deg   = (int*)(sdst2 + N);               // N (reused as cursor)
    int*      rowst = deg + N;                         // N+1
    int*      bsums = rowst + N + 1;                   // 64
    int*      adj   = bsums + 64;                      // ET

    const int B = 256;
    auto blocks = [](size_t n, int b) { return (int)((n + b - 1) / b); };
    const int nscan = (N + SCAN_ELEMS - 1) / SCAN_ELEMS;

    // ---- converts ----
    cvt_pack_k<<<blocks((size_t)N * 64, B), B, 0, stream>>>(x, xb, (size_t)N * 64);
    wcvt_k<128, 256><<<blocks(128 * 256, B), B, 0, stream>>>(W1, (unsigned short*)Wt1);
    wcvt_k<256, 128><<<blocks(256 * 128, B), B, 0, stream>>>(W2, (unsigned short*)Wt2);

    // ---- CSR build ----
    fill_i32_k<<<blocks(N, B), B, 0, stream>>>(deg, N, 1);
    count_k<<<blocks(E, B), B, 0, stream>>>(dst, E, deg);
    scan1_k<<<nscan, SCAN_BLK, 0, stream>>>(deg, rowst, bsums, N);
    scan2_k<<<1, 64, 0, stream>>>(bsums, nscan);
    scan3_k<<<blocks(N + 1, B), B, 0, stream>>>(rowst, bsums, N, ET);
    initadj_k<<<blocks(N, B), B, 0, stream>>>(rowst, adj, deg, N);
    scatter_k<<<blocks(E, B), B, 0, stream>>>(src, dst, E, deg, adj);

    // ---- layer 1 ----
    {
        dim3 g((N + 127) / 128, 256 / 64);
        gemm_mfma_k<128, 256><<<g, 256, 0, stream>>>(xb, (const unsigned*)Wt1, (unsigned short*)h1b, N);
    }
    score_b_k<4, 64><<<blocks((size_t)N * 4, B), B, 0, stream>>>(h1b, as1, ad1, ssrc1, sdst1, N);
    node_agg_k<4, 64, true, true><<<(N + 3) / 4, 256, 0, stream>>>(rowst, adj, ssrc1, sdst1, h1b, b1, agg1b, N);

    // ---- layer 2 ----
    {
        dim3 g((N + 127) / 128, 128 / 64);
        gemm_mfma_k<256, 128><<<g, 256, 0, stream>>>(agg1b, (const unsigned*)Wt2, (unsigned short*)h2b, N);
    }
    score_b_k<1, 128><<<blocks(N, B), B, 0, stream>>>(h2b, as2, ad2, ssrc2, sdst2, N);
    node_agg_k<1, 128, false, false><<<(N + 3) / 4, 256, 0, stream>>>(rowst, adj, ssrc2, sdst2, h2b, b2, out, N);
}

// Round 5
// 297.141 us; speedup vs baseline: 2.0280x; 1.1140x over previous
//
#include <hip/hip_runtime.h>
#include <cmath>

typedef __attribute__((ext_vector_type(8))) short bf16x8;
typedef __attribute__((ext_vector_type(4))) float f32x4;

// ---------- bf16 pack/unpack ----------
static __device__ __forceinline__ unsigned short f2bf(float f) {
    unsigned u = __float_as_uint(f);
    unsigned r = (u + 0x7fffu + ((u >> 16) & 1u)) >> 16;   // RNE
    return (unsigned short)r;
}
static __device__ __forceinline__ unsigned packbf(float a, float b) {
    return (unsigned)f2bf(a) | ((unsigned)f2bf(b) << 16);
}
static __device__ __forceinline__ float bflo(unsigned u) { return __uint_as_float(u << 16); }
static __device__ __forceinline__ float bfhi(unsigned u) { return __uint_as_float(u & 0xffff0000u); }

// ---------- fills / converts ----------
__global__ void fill_i32_k(int* __restrict__ p, size_t n, int v) {
    size_t i = (size_t)blockIdx.x * blockDim.x + threadIdx.x;
    if (i < n) p[i] = v;
}
__global__ void cvt_pack_k(const float* __restrict__ X, unsigned* __restrict__ Xb, size_t n2) {
    size_t i = (size_t)blockIdx.x * blockDim.x + threadIdx.x;
    if (i >= n2) return;
    float2 v = reinterpret_cast<const float2*>(X)[i];
    Xb[i] = packbf(v.x, v.y);
}
template<int K, int NOUT>
__global__ void wcvt_k(const float* __restrict__ W, unsigned short* __restrict__ Wt) {
    int i = blockIdx.x * blockDim.x + threadIdx.x;   // over K*NOUT, n-major
    if (i >= K * NOUT) return;
    int n = i / K, k = i % K;
    Wt[i] = f2bf(W[(size_t)k * NOUT + n]);
}

// ---------- CSR build ----------
__global__ void count_k(const int* __restrict__ dst, int E, int* __restrict__ deg) {
    int e = blockIdx.x * blockDim.x + threadIdx.x;
    if (e < E) atomicAdd(&deg[dst[e]], 1);
}

#define SCAN_BLK 256
#define SCAN_ELEMS 2048

__global__ void scan1_k(const int* __restrict__ deg, int* __restrict__ rowstart,
                        int* __restrict__ bsums, int N) {
    __shared__ int sh[SCAN_BLK];
    int t = threadIdx.x;
    int base = blockIdx.x * SCAN_ELEMS + t * 8;
    int vals[8];
    int sum = 0;
#pragma unroll
    for (int i = 0; i < 8; ++i) {
        int idx = base + i;
        vals[i] = (idx < N) ? deg[idx] : 0;
        sum += vals[i];
    }
    sh[t] = sum;
    __syncthreads();
    for (int off = 1; off < SCAN_BLK; off <<= 1) {
        int v = (t >= off) ? sh[t - off] : 0;
        __syncthreads();
        sh[t] += v;
        __syncthreads();
    }
    int run = sh[t] - sum;
    if (t == SCAN_BLK - 1) bsums[blockIdx.x] = sh[t];
#pragma unroll
    for (int i = 0; i < 8; ++i) {
        int idx = base + i;
        if (idx < N) rowstart[idx] = run;
        run += vals[i];
    }
}
__global__ void scan2_k(int* __restrict__ bsums, int nb) {
    if (threadIdx.x == 0 && blockIdx.x == 0) {
        int run = 0;
        for (int i = 0; i < nb; ++i) { int t = bsums[i]; bsums[i] = run; run += t; }
    }
}
__global__ void scan3_k(int* __restrict__ rowstart, const int* __restrict__ bsums, int N, int total) {
    int i = blockIdx.x * blockDim.x + threadIdx.x;
    if (i < N) rowstart[i] += bsums[i / SCAN_ELEMS];
    else if (i == N) rowstart[N] = total;
}
__global__ void initadj_k(const int* __restrict__ rowstart, int* __restrict__ adj,
                          int* __restrict__ cursor, int N) {
    int n = blockIdx.x * blockDim.x + threadIdx.x;
    if (n >= N) return;
    int r = rowstart[n];
    adj[r] = n;
    cursor[n] = r + 1;
}
__global__ void scatter_k(const int* __restrict__ src, const int* __restrict__ dst, int E,
                          int* __restrict__ cursor, int* __restrict__ adj) {
    int e = blockIdx.x * blockDim.x + threadIdx.x;
    if (e >= E) return;
    int pos = atomicAdd(&cursor[dst[e]], 1);
    adj[pos] = src[e];
}

// ---------- MFMA GEMM: Yb[N,NOUT](bf16) = Ab[N,K](bf16) @ Wt[NOUT,K](bf16)^T ----------
template<int K, int NOUT>
__global__ __launch_bounds__(256) void gemm_mfma_k(const unsigned* __restrict__ Ab,
                                                   const unsigned* __restrict__ Bt,
                                                   unsigned short* __restrict__ Yb, int N) {
    __shared__ unsigned short As[128 * 64];
    __shared__ unsigned short Bs[64 * 64];
    int tid = threadIdx.x;
    int lane = tid & 63, wid = tid >> 6;
    int wm = wid >> 1, wc = wid & 1;
    int m0 = blockIdx.x * 128;
    int n0 = blockIdx.y * 64;

    f32x4 acc[4][2] = {};

    for (int k0 = 0; k0 < K; k0 += 64) {
#pragma unroll
        for (int p = 0; p < 4; ++p) {
            int gl = p * 256 + tid;
            int row = gl >> 3, g = gl & 7;
            int grow = m0 + row; if (grow >= N) grow = N - 1;
            uint4 v = *reinterpret_cast<const uint4*>(Ab + (size_t)grow * (K / 2) + k0 / 2 + g * 4);
            *reinterpret_cast<uint4*>((char*)As + row * 128 + ((g ^ (row & 7)) << 4)) = v;
        }
#pragma unroll
        for (int p = 0; p < 2; ++p) {
            int gl = p * 256 + tid;
            int row = gl >> 3, g = gl & 7;
            uint4 v = *reinterpret_cast<const uint4*>(Bt + (size_t)(n0 + row) * (K / 2) + k0 / 2 + g * 4);
            *reinterpret_cast<uint4*>((char*)Bs + row * 128 + ((g ^ (row & 7)) << 4)) = v;
        }
        __syncthreads();

        bf16x8 bfrag[2][2];
#pragma unroll
        for (int kk = 0; kk < 2; ++kk)
#pragma unroll
            for (int no = 0; no < 2; ++no) {
                int row = wc * 32 + no * 16 + (lane & 15);
                int g = kk * 4 + (lane >> 4);
                bfrag[kk][no] = *reinterpret_cast<const bf16x8*>((char*)Bs + row * 128 + ((g ^ (row & 7)) << 4));
            }
#pragma unroll
        for (int mo = 0; mo < 4; ++mo) {
#pragma unroll
            for (int kk = 0; kk < 2; ++kk) {
                int row = wm * 64 + mo * 16 + (lane & 15);
                int g = kk * 4 + (lane >> 4);
                bf16x8 afrag = *reinterpret_cast<const bf16x8*>((char*)As + row * 128 + ((g ^ (row & 7)) << 4));
                acc[mo][0] = __builtin_amdgcn_mfma_f32_16x16x32_bf16(afrag, bfrag[kk][0], acc[mo][0], 0, 0, 0);
                acc[mo][1] = __builtin_amdgcn_mfma_f32_16x16x32_bf16(afrag, bfrag[kk][1], acc[mo][1], 0, 0, 0);
            }
        }
        __syncthreads();
    }
#pragma unroll
    for (int mo = 0; mo < 4; ++mo)
#pragma unroll
        for (int no = 0; no < 2; ++no) {
            int col = n0 + wc * 32 + no * 16 + (lane & 15);
            int rbase = m0 + wm * 64 + mo * 16 + (lane >> 4) * 4;
#pragma unroll
            for (int j = 0; j < 4; ++j) {
                int row = rbase + j;
                if (row < N) Yb[(size_t)row * NOUT + col] = f2bf(acc[mo][no][j]);
            }
        }
}

// ---------- attention scores from packed-bf16 features ----------
template<int H, int C>
__global__ void score_b_k(const unsigned* __restrict__ hb, const float* __restrict__ a_src,
                          const float* __restrict__ a_dst,
                          float* __restrict__ ssrc, float* __restrict__ sdst, int N) {
    int idx = blockIdx.x * blockDim.x + threadIdx.x;
    if (idx >= N * H) return;
    int n = idx / H, hh = idx % H;
    const uint4* hp = reinterpret_cast<const uint4*>(hb + (size_t)n * (H * C / 2) + hh * (C / 2));
    const float* as = a_src + hh * C;
    const float* ad = a_dst + hh * C;
    float ss = 0.f, sd = 0.f;
#pragma unroll
    for (int i = 0; i < C / 8; ++i) {
        uint4 u = hp[i];
        float v[8] = {bflo(u.x), bfhi(u.x), bflo(u.y), bfhi(u.y),
                      bflo(u.z), bfhi(u.z), bflo(u.w), bfhi(u.w)};
#pragma unroll
        for (int j = 0; j < 8; ++j) { ss += v[j] * as[i * 8 + j]; sd += v[j] * ad[i * 8 + j]; }
    }
    ssrc[idx] = ss;
    sdst[idx] = sd;
}

// ---------- fused per-node softmax + bf16 gather-aggregate + epilogue ----------
// Fast path (deg<=64): one edge per lane, exact softmax with 1 exp/edge/head,
// alpha broadcast via shuffles in pass 2 (no redundant exp, no ssrc regather).
template<int H, int C, bool ELU, bool OUT_BF16>
__global__ void node_agg_k(const int* __restrict__ rowstart, const int* __restrict__ adj,
                           const float* __restrict__ ssrc, const float* __restrict__ sdst,
                           const unsigned* __restrict__ hb, const float* __restrict__ bias,
                           void* __restrict__ outp, int N) {
    constexpr int HC = H * C;
    constexpr int FPL = HC / 64;            // 4 or 2
    constexpr int UPL = FPL / 2;            // 2 or 1
    int lane = threadIdx.x & 63;
    int n = blockIdx.x * (blockDim.x >> 6) + (threadIdx.x >> 6);
    if (n >= N) return;
    int r0 = rowstart[n], r1 = rowstart[n + 1];
    int deg = r1 - r0;

    float sd[H];
#pragma unroll
    for (int h = 0; h < H; ++h) sd[h] = sdst[n * H + h];

    int hA = (lane * FPL) / C;
    float acc[FPL];
#pragma unroll
    for (int f = 0; f < FPL; ++f) acc[f] = 0.f;

    if (deg <= 64) {
        // ---- fast path ----
        int s = adj[r0 + ((lane < deg) ? lane : 0)];
        float a[H];
        {
            float v[H];
            if constexpr (H == 4) {
                float4 sv = reinterpret_cast<const float4*>(ssrc)[s];
                v[0] = sv.x; v[1] = sv.y; v[2] = sv.z; v[3] = sv.w;
            } else {
                v[0] = ssrc[s];
            }
#pragma unroll
            for (int h = 0; h < H; ++h) {
                float t = v[h] + sd[h];
                t = t > 0.f ? t : 0.2f * t;
                v[h] = (lane < deg) ? t : -1e30f;
            }
            float m[H], l[H];
#pragma unroll
            for (int h = 0; h < H; ++h) m[h] = v[h];
#pragma unroll
            for (int off = 32; off; off >>= 1)
#pragma unroll
                for (int h = 0; h < H; ++h)
                    m[h] = fmaxf(m[h], __shfl_xor(m[h], off, 64));
#pragma unroll
            for (int h = 0; h < H; ++h) {
                a[h] = (lane < deg) ? __expf(v[h] - m[h]) : 0.f;
                l[h] = a[h];
            }
#pragma unroll
            for (int off = 32; off; off >>= 1)
#pragma unroll
                for (int h = 0; h < H; ++h)
                    l[h] += __shfl_xor(l[h], off, 64);
#pragma unroll
            for (int h = 0; h < H; ++h) a[h] *= __builtin_amdgcn_rcpf(l[h]);
        }

        auto body = [&](int j) {
            float alpha;
            if constexpr (H == 4) {
                float a0 = __shfl(a[0], j, 64);
                float a1 = __shfl(a[1], j, 64);
                float a2 = __shfl(a[2], j, 64);
                float a3 = __shfl(a[3], j, 64);
                alpha = hA == 0 ? a0 : hA == 1 ? a1 : hA == 2 ? a2 : a3;
            } else {
                alpha = __shfl(a[0], j, 64);
            }
            int sj = __shfl(s, j, 64);
            const unsigned* hp = hb + (size_t)sj * (HC / 2) + lane * UPL;
            if constexpr (UPL == 2) {
                uint2 u = *reinterpret_cast<const uint2*>(hp);
                acc[0] += alpha * bflo(u.x); acc[1] += alpha * bfhi(u.x);
                acc[2] += alpha * bflo(u.y); acc[3] += alpha * bfhi(u.y);
            } else {
                unsigned u = *hp;
                acc[0] += alpha * bflo(u); acc[1] += alpha * bfhi(u);
            }
        };
        int j = 0;
        for (; j + 1 < deg; j += 2) { body(j); body(j + 1); }
        if (j < deg) body(j);
    } else {
        // ---- general path (deg > 64): online softmax + recompute ----
        float m[H], l[H];
#pragma unroll
        for (int h = 0; h < H; ++h) { m[h] = -1e30f; l[h] = 0.f; }
        for (int e = r0 + lane; e < r1; e += 64) {
            int s = adj[e];
#pragma unroll
            for (int h = 0; h < H; ++h) {
                float v = ssrc[s * H + h] + sd[h];
                v = v > 0.f ? v : 0.2f * v;
                float mn = fmaxf(m[h], v);
                l[h] = l[h] * __expf(m[h] - mn) + __expf(v - mn);
                m[h] = mn;
            }
        }
#pragma unroll
        for (int off = 32; off; off >>= 1)
#pragma unroll
            for (int h = 0; h < H; ++h) {
                float mo = __shfl_xor(m[h], off, 64);
                float lo = __shfl_xor(l[h], off, 64);
                float mn = fmaxf(m[h], mo);
                l[h] = l[h] * __expf(m[h] - mn) + lo * __expf(mo - mn);
                m[h] = mn;
            }
        float mh = m[hA], invl = 1.f / l[hA], sdh = sd[hA];
        for (int e = r0; e < r1; ++e) {
            int s = adj[e];
            float v = ssrc[s * H + hA] + sdh;
            v = v > 0.f ? v : 0.2f * v;
            float alpha = __expf(v - mh) * invl;
            const unsigned* hp = hb + (size_t)s * (HC / 2) + lane * UPL;
            if constexpr (UPL == 2) {
                uint2 u = *reinterpret_cast<const uint2*>(hp);
                acc[0] += alpha * bflo(u.x); acc[1] += alpha * bfhi(u.x);
                acc[2] += alpha * bflo(u.y); acc[3] += alpha * bfhi(u.y);
            } else {
                unsigned u = *hp;
                acc[0] += alpha * bflo(u); acc[1] += alpha * bfhi(u);
            }
        }
    }

#pragma unroll
    for (int f = 0; f < FPL; ++f) {
        float v = acc[f] + bias[lane * FPL + f];
        if (ELU) v = v > 0.f ? v : (__expf(v) - 1.f);
        acc[f] = v;
    }
    if constexpr (OUT_BF16) {
        unsigned* op = (unsigned*)outp + (size_t)n * (HC / 2) + lane * UPL;
        if constexpr (UPL == 2) {
            uint2 u = {packbf(acc[0], acc[1]), packbf(acc[2], acc[3])};
            *reinterpret_cast<uint2*>(op) = u;
        } else {
            *op = packbf(acc[0], acc[1]);
        }
    } else {
        float* op = (float*)outp + (size_t)n * HC + lane * FPL;
        if constexpr (FPL == 2) {
            *reinterpret_cast<float2*>(op) = make_float2(acc[0], acc[1]);
        } else {
#pragma unroll
            for (int f = 0; f < FPL; ++f) op[f] = acc[f];
        }
    }
}

// ---------- launch ----------
extern "C" void kernel_launch(void* const* d_in, const int* in_sizes, int n_in,
                              void* d_out, int out_size, void* d_ws, size_t ws_size,
                              hipStream_t stream) {
    const float* x   = (const float*)d_in[0];
    const int*   ei  = (const int*)d_in[1];
    const float* W1  = (const float*)d_in[2];
    const float* as1 = (const float*)d_in[3];
    const float* ad1 = (const float*)d_in[4];
    const float* b1  = (const float*)d_in[5];
    const float* W2  = (const float*)d_in[6];
    const float* as2 = (const float*)d_in[7];
    const float* ad2 = (const float*)d_in[8];
    const float* b2  = (const float*)d_in[9];
    float* out = (float*)d_out;

    const int N  = in_sizes[0] / 128;   // 50000
    const int E  = in_sizes[1] / 2;     // 800000
    const int ET = E + N;
    const int* src = ei;
    const int* dst = ei + E;

    // workspace (4B units)
    unsigned* ws = (unsigned*)d_ws;
    unsigned* xb    = ws;                              // N*64  (x bf16)
    unsigned* h1b   = xb    + (size_t)N * 64;          // N*128
    unsigned* agg1b = h1b   + (size_t)N * 128;         // N*128
    unsigned* h2b   = agg1b + (size_t)N * 128;         // N*64
    unsigned* Wt1   = h2b   + (size_t)N * 64;          // 16384
    unsigned* Wt2   = Wt1   + 16384;                   // 16384
    float*    ssrc1 = (float*)(Wt2 + 16384);           // N*4
    float*    sdst1 = ssrc1 + (size_t)N * 4;           // N*4
    float*    ssrc2 = sdst1 + (size_t)N * 4;           // N
    float*    sdst2 = ssrc2 + N;                       // N
    int*      deg   = (int*)(sdst2 + N);               // N (reused as cursor)
    int*      rowst = deg + N;                         // N+1
    int*      bsums = rowst + N + 1;                   // 64
    int*      adj   = bsums + 64;                      // ET

    const int B = 256;
    auto blocks = [](size_t n, int b) { return (int)((n + b - 1) / b); };
    const int nscan = (N + SCAN_ELEMS - 1) / SCAN_ELEMS;

    // ---- converts ----
    cvt_pack_k<<<blocks((size_t)N * 64, B), B, 0, stream>>>(x, xb, (size_t)N * 64);
    wcvt_k<128, 256><<<blocks(128 * 256, B), B, 0, stream>>>(W1, (unsigned short*)Wt1);
    wcvt_k<256, 128><<<blocks(256 * 128, B), B, 0, stream>>>(W2, (unsigned short*)Wt2);

    // ---- CSR build ----
    fill_i32_k<<<blocks(N, B), B, 0, stream>>>(deg, N, 1);
    count_k<<<blocks(E, B), B, 0, stream>>>(dst, E, deg);
    scan1_k<<<nscan, SCAN_BLK, 0, stream>>>(deg, rowst, bsums, N);
    scan2_k<<<1, 64, 0, stream>>>(bsums, nscan);
    scan3_k<<<blocks(N + 1, B), B, 0, stream>>>(rowst, bsums, N, ET);
    initadj_k<<<blocks(N, B), B, 0, stream>>>(rowst, adj, deg, N);
    scatter_k<<<blocks(E, B), B, 0, stream>>>(src, dst, E, deg, adj);

    // ---- layer 1 ----
    {
        dim3 g((N + 127) / 128, 256 / 64);
        gemm_mfma_k<128, 256><<<g, 256, 0, stream>>>(xb, (const unsigned*)Wt1, (unsigned short*)h1b, N);
    }
    score_b_k<4, 64><<<blocks((size_t)N * 4, B), B, 0, stream>>>(h1b, as1, ad1, ssrc1, sdst1, N);
    node_agg_k<4, 64, true, true><<<(N + 3) / 4, 256, 0, stream>>>(rowst, adj, ssrc1, sdst1, h1b, b1, agg1b, N);

    // ---- layer 2 ----
    {
        dim3 g((N + 127) / 128, 128 / 64);
        gemm_mfma_k<256, 128><<<g, 256, 0, stream>>>(agg1b, (const unsigned*)Wt2, (unsigned short*)h2b, N);
    }
    score_b_k<1, 128><<<blocks(N, B), B, 0, stream>>>(h2b, as2, ad2, ssrc2, sdst2, N);
    node_agg_k<1, 128, false, false><<<(N + 3) / 4, 256, 0, stream>>>(rowst, adj, ssrc2, sdst2, h2b, b2, out, N);
}

// Round 6
// 273.756 us; speedup vs baseline: 2.2013x; 1.0854x over previous
//
#include <hip/hip_runtime.h>
#include <cmath>

typedef __attribute__((ext_vector_type(8))) short bf16x8;
typedef __attribute__((ext_vector_type(4))) float f32x4;

// ---------- bf16 pack/unpack ----------
static __device__ __forceinline__ unsigned short f2bf(float f) {
    unsigned u = __float_as_uint(f);
    unsigned r = (u + 0x7fffu + ((u >> 16) & 1u)) >> 16;   // RNE
    return (unsigned short)r;
}
static __device__ __forceinline__ unsigned packbf(float a, float b) {
    return (unsigned)f2bf(a) | ((unsigned)f2bf(b) << 16);
}
static __device__ __forceinline__ float bflo(unsigned u) { return __uint_as_float(u << 16); }
static __device__ __forceinline__ float bfhi(unsigned u) { return __uint_as_float(u & 0xffff0000u); }
static __device__ __forceinline__ float rlanef(float v, int j) {
    return __uint_as_float(__builtin_amdgcn_readlane(__float_as_uint(v), j));
}

// ---------- fills / converts ----------
__global__ void fill_i32_k(int* __restrict__ p, size_t n, int v) {
    size_t i = (size_t)blockIdx.x * blockDim.x + threadIdx.x;
    if (i < n) p[i] = v;
}
__global__ void cvt_pack_k(const float* __restrict__ X, unsigned* __restrict__ Xb, size_t n2) {
    size_t i = (size_t)blockIdx.x * blockDim.x + threadIdx.x;
    if (i >= n2) return;
    float2 v = reinterpret_cast<const float2*>(X)[i];
    Xb[i] = packbf(v.x, v.y);
}
template<int K, int NOUT>
__global__ void wcvt_k(const float* __restrict__ W, unsigned short* __restrict__ Wt) {
    int i = blockIdx.x * blockDim.x + threadIdx.x;   // over K*NOUT, n-major
    if (i >= K * NOUT) return;
    int n = i / K, k = i % K;
    Wt[i] = f2bf(W[(size_t)k * NOUT + n]);
}

// ---------- CSR build ----------
__global__ void count_k(const int* __restrict__ dst, int E, int* __restrict__ deg) {
    int e = blockIdx.x * blockDim.x + threadIdx.x;
    if (e < E) atomicAdd(&deg[dst[e]], 1);
}

#define SCAN_BLK 256
#define SCAN_ELEMS 2048

__global__ void scan1_k(const int* __restrict__ deg, int* __restrict__ rowstart,
                        int* __restrict__ bsums, int N) {
    __shared__ int sh[SCAN_BLK];
    int t = threadIdx.x;
    int base = blockIdx.x * SCAN_ELEMS + t * 8;
    int vals[8];
    int sum = 0;
#pragma unroll
    for (int i = 0; i < 8; ++i) {
        int idx = base + i;
        vals[i] = (idx < N) ? deg[idx] : 0;
        sum += vals[i];
    }
    sh[t] = sum;
    __syncthreads();
    for (int off = 1; off < SCAN_BLK; off <<= 1) {
        int v = (t >= off) ? sh[t - off] : 0;
        __syncthreads();
        sh[t] += v;
        __syncthreads();
    }
    int run = sh[t] - sum;
    if (t == SCAN_BLK - 1) bsums[blockIdx.x] = sh[t];
#pragma unroll
    for (int i = 0; i < 8; ++i) {
        int idx = base + i;
        if (idx < N) rowstart[idx] = run;
        run += vals[i];
    }
}
__global__ void scan2_k(int* __restrict__ bsums, int nb) {
    if (threadIdx.x == 0 && blockIdx.x == 0) {
        int run = 0;
        for (int i = 0; i < nb; ++i) { int t = bsums[i]; bsums[i] = run; run += t; }
    }
}
__global__ void scan3_k(int* __restrict__ rowstart, const int* __restrict__ bsums, int N, int total) {
    int i = blockIdx.x * blockDim.x + threadIdx.x;
    if (i < N) rowstart[i] += bsums[i / SCAN_ELEMS];
    else if (i == N) rowstart[N] = total;
}
__global__ void initadj_k(const int* __restrict__ rowstart, int* __restrict__ adj,
                          int* __restrict__ cursor, int N) {
    int n = blockIdx.x * blockDim.x + threadIdx.x;
    if (n >= N) return;
    int r = rowstart[n];
    adj[r] = n;
    cursor[n] = r + 1;
}
__global__ void scatter_k(const int* __restrict__ src, const int* __restrict__ dst, int E,
                          int* __restrict__ cursor, int* __restrict__ adj) {
    int e = blockIdx.x * blockDim.x + threadIdx.x;
    if (e >= E) return;
    int pos = atomicAdd(&cursor[dst[e]], 1);
    adj[pos] = src[e];
}

// ---------- MFMA GEMM: Yb[N,NOUT](bf16) = Ab[N,K](bf16) @ Wt[NOUT,K](bf16)^T ----------
template<int K, int NOUT>
__global__ __launch_bounds__(256) void gemm_mfma_k(const unsigned* __restrict__ Ab,
                                                   const unsigned* __restrict__ Bt,
                                                   unsigned short* __restrict__ Yb, int N) {
    __shared__ unsigned short As[128 * 64];
    __shared__ unsigned short Bs[64 * 64];
    int tid = threadIdx.x;
    int lane = tid & 63, wid = tid >> 6;
    int wm = wid >> 1, wc = wid & 1;
    int m0 = blockIdx.x * 128;
    int n0 = blockIdx.y * 64;

    f32x4 acc[4][2] = {};

    for (int k0 = 0; k0 < K; k0 += 64) {
#pragma unroll
        for (int p = 0; p < 4; ++p) {
            int gl = p * 256 + tid;
            int row = gl >> 3, g = gl & 7;
            int grow = m0 + row; if (grow >= N) grow = N - 1;
            uint4 v = *reinterpret_cast<const uint4*>(Ab + (size_t)grow * (K / 2) + k0 / 2 + g * 4);
            *reinterpret_cast<uint4*>((char*)As + row * 128 + ((g ^ (row & 7)) << 4)) = v;
        }
#pragma unroll
        for (int p = 0; p < 2; ++p) {
            int gl = p * 256 + tid;
            int row = gl >> 3, g = gl & 7;
            uint4 v = *reinterpret_cast<const uint4*>(Bt + (size_t)(n0 + row) * (K / 2) + k0 / 2 + g * 4);
            *reinterpret_cast<uint4*>((char*)Bs + row * 128 + ((g ^ (row & 7)) << 4)) = v;
        }
        __syncthreads();

        bf16x8 bfrag[2][2];
#pragma unroll
        for (int kk = 0; kk < 2; ++kk)
#pragma unroll
            for (int no = 0; no < 2; ++no) {
                int row = wc * 32 + no * 16 + (lane & 15);
                int g = kk * 4 + (lane >> 4);
                bfrag[kk][no] = *reinterpret_cast<const bf16x8*>((char*)Bs + row * 128 + ((g ^ (row & 7)) << 4));
            }
#pragma unroll
        for (int mo = 0; mo < 4; ++mo) {
#pragma unroll
            for (int kk = 0; kk < 2; ++kk) {
                int row = wm * 64 + mo * 16 + (lane & 15);
                int g = kk * 4 + (lane >> 4);
                bf16x8 afrag = *reinterpret_cast<const bf16x8*>((char*)As + row * 128 + ((g ^ (row & 7)) << 4));
                acc[mo][0] = __builtin_amdgcn_mfma_f32_16x16x32_bf16(afrag, bfrag[kk][0], acc[mo][0], 0, 0, 0);
                acc[mo][1] = __builtin_amdgcn_mfma_f32_16x16x32_bf16(afrag, bfrag[kk][1], acc[mo][1], 0, 0, 0);
            }
        }
        __syncthreads();
    }
#pragma unroll
    for (int mo = 0; mo < 4; ++mo)
#pragma unroll
        for (int no = 0; no < 2; ++no) {
            int col = n0 + wc * 32 + no * 16 + (lane & 15);
            int rbase = m0 + wm * 64 + mo * 16 + (lane >> 4) * 4;
#pragma unroll
            for (int j = 0; j < 4; ++j) {
                int row = rbase + j;
                if (row < N) Yb[(size_t)row * NOUT + col] = f2bf(acc[mo][no][j]);
            }
        }
}

// ---------- attention scores from packed-bf16 features ----------
template<int H, int C>
__global__ void score_b_k(const unsigned* __restrict__ hb, const float* __restrict__ a_src,
                          const float* __restrict__ a_dst,
                          float* __restrict__ ssrc, float* __restrict__ sdst, int N) {
    int idx = blockIdx.x * blockDim.x + threadIdx.x;
    if (idx >= N * H) return;
    int n = idx / H, hh = idx % H;
    const uint4* hp = reinterpret_cast<const uint4*>(hb + (size_t)n * (H * C / 2) + hh * (C / 2));
    const float* as = a_src + hh * C;
    const float* ad = a_dst + hh * C;
    float ss = 0.f, sd = 0.f;
#pragma unroll
    for (int i = 0; i < C / 8; ++i) {
        uint4 u = hp[i];
        float v[8] = {bflo(u.x), bfhi(u.x), bflo(u.y), bfhi(u.y),
                      bflo(u.z), bfhi(u.z), bflo(u.w), bfhi(u.w)};
#pragma unroll
        for (int j = 0; j < 8; ++j) { ss += v[j] * as[i * 8 + j]; sd += v[j] * ad[i * 8 + j]; }
    }
    ssrc[idx] = ss;
    sdst[idx] = sd;
}

// ---------- fused per-node softmax + bf16 gather-aggregate + epilogue ----------
// Fast path (deg<=64): one edge per lane; softmax via butterfly; pass 2 uses
// v_readlane (uniform j) for alpha+src -> scalar row base, 4 loads in flight.
template<int H, int C, bool ELU, bool OUT_BF16>
__global__ void node_agg_k(const int* __restrict__ rowstart, const int* __restrict__ adj,
                           const float* __restrict__ ssrc, const float* __restrict__ sdst,
                           const unsigned* __restrict__ hb, const float* __restrict__ bias,
                           void* __restrict__ outp, int N) {
    constexpr int HC = H * C;
    constexpr int FPL = HC / 64;            // 4 or 2
    constexpr int UPL = FPL / 2;            // 2 or 1
    int lane = threadIdx.x & 63;
    int n = blockIdx.x * (blockDim.x >> 6) + (threadIdx.x >> 6);
    if (n >= N) return;
    int r0 = rowstart[n], r1 = rowstart[n + 1];
    int deg = r1 - r0;

    float sd[H];
#pragma unroll
    for (int h = 0; h < H; ++h) sd[h] = sdst[n * H + h];

    int hA = (lane * FPL) / C;
    float acc[FPL];
#pragma unroll
    for (int f = 0; f < FPL; ++f) acc[f] = 0.f;

    if (deg <= 64) {
        // ---- fast path ----
        int s = adj[r0 + ((lane < deg) ? lane : 0)];
        float a[H];
        {
            float v[H];
            if constexpr (H == 4) {
                float4 sv = reinterpret_cast<const float4*>(ssrc)[s];
                v[0] = sv.x; v[1] = sv.y; v[2] = sv.z; v[3] = sv.w;
            } else {
                v[0] = ssrc[s];
            }
#pragma unroll
            for (int h = 0; h < H; ++h) {
                float t = v[h] + sd[h];
                t = t > 0.f ? t : 0.2f * t;
                v[h] = (lane < deg) ? t : -1e30f;
            }
            float m[H], l[H];
#pragma unroll
            for (int h = 0; h < H; ++h) m[h] = v[h];
#pragma unroll
            for (int off = 32; off; off >>= 1)
#pragma unroll
                for (int h = 0; h < H; ++h)
                    m[h] = fmaxf(m[h], __shfl_xor(m[h], off, 64));
#pragma unroll
            for (int h = 0; h < H; ++h) {
                a[h] = (lane < deg) ? __expf(v[h] - m[h]) : 0.f;
                l[h] = a[h];
            }
#pragma unroll
            for (int off = 32; off; off >>= 1)
#pragma unroll
                for (int h = 0; h < H; ++h)
                    l[h] += __shfl_xor(l[h], off, 64);
#pragma unroll
            for (int h = 0; h < H; ++h) a[h] *= __builtin_amdgcn_rcpf(l[h]);
        }

        // alpha for edge j, selected for this lane's head (readlane: j uniform)
        auto alpha_of = [&](int j) -> float {
            if constexpr (H == 4) {
                float a0 = rlanef(a[0], j), a1 = rlanef(a[1], j);
                float a2 = rlanef(a[2], j), a3 = rlanef(a[3], j);
                return hA == 0 ? a0 : hA == 1 ? a1 : hA == 2 ? a2 : a3;
            } else {
                return rlanef(a[0], j);
            }
        };

        int j = 0;
        for (; j + 4 <= deg; j += 4) {
            int s0 = __builtin_amdgcn_readlane(s, j + 0);
            int s1 = __builtin_amdgcn_readlane(s, j + 1);
            int s2 = __builtin_amdgcn_readlane(s, j + 2);
            int s3 = __builtin_amdgcn_readlane(s, j + 3);
            if constexpr (UPL == 2) {
                uint2 u0 = *reinterpret_cast<const uint2*>(hb + (size_t)s0 * (HC / 2) + lane * 2);
                uint2 u1 = *reinterpret_cast<const uint2*>(hb + (size_t)s1 * (HC / 2) + lane * 2);
                uint2 u2 = *reinterpret_cast<const uint2*>(hb + (size_t)s2 * (HC / 2) + lane * 2);
                uint2 u3 = *reinterpret_cast<const uint2*>(hb + (size_t)s3 * (HC / 2) + lane * 2);
                float al0 = alpha_of(j + 0), al1 = alpha_of(j + 1);
                float al2 = alpha_of(j + 2), al3 = alpha_of(j + 3);
                acc[0] += al0 * bflo(u0.x); acc[1] += al0 * bfhi(u0.x);
                acc[2] += al0 * bflo(u0.y); acc[3] += al0 * bfhi(u0.y);
                acc[0] += al1 * bflo(u1.x); acc[1] += al1 * bfhi(u1.x);
                acc[2] += al1 * bflo(u1.y); acc[3] += al1 * bfhi(u1.y);
                acc[0] += al2 * bflo(u2.x); acc[1] += al2 * bfhi(u2.x);
                acc[2] += al2 * bflo(u2.y); acc[3] += al2 * bfhi(u2.y);
                acc[0] += al3 * bflo(u3.x); acc[1] += al3 * bfhi(u3.x);
                acc[2] += al3 * bflo(u3.y); acc[3] += al3 * bfhi(u3.y);
            } else {
                unsigned u0 = hb[(size_t)s0 * (HC / 2) + lane];
                unsigned u1 = hb[(size_t)s1 * (HC / 2) + lane];
                unsigned u2 = hb[(size_t)s2 * (HC / 2) + lane];
                unsigned u3 = hb[(size_t)s3 * (HC / 2) + lane];
                float al0 = alpha_of(j + 0), al1 = alpha_of(j + 1);
                float al2 = alpha_of(j + 2), al3 = alpha_of(j + 3);
                acc[0] += al0 * bflo(u0); acc[1] += al0 * bfhi(u0);
                acc[0] += al1 * bflo(u1); acc[1] += al1 * bfhi(u1);
                acc[0] += al2 * bflo(u2); acc[1] += al2 * bfhi(u2);
                acc[0] += al3 * bflo(u3); acc[1] += al3 * bfhi(u3);
            }
        }
        for (; j < deg; ++j) {
            int sj = __builtin_amdgcn_readlane(s, j);
            float al = alpha_of(j);
            const unsigned* hp = hb + (size_t)sj * (HC / 2) + lane * UPL;
            if constexpr (UPL == 2) {
                uint2 u = *reinterpret_cast<const uint2*>(hp);
                acc[0] += al * bflo(u.x); acc[1] += al * bfhi(u.x);
                acc[2] += al * bflo(u.y); acc[3] += al * bfhi(u.y);
            } else {
                unsigned u = *hp;
                acc[0] += al * bflo(u); acc[1] += al * bfhi(u);
            }
        }
    } else {
        // ---- general path (deg > 64): online softmax + recompute ----
        float m[H], l[H];
#pragma unroll
        for (int h = 0; h < H; ++h) { m[h] = -1e30f; l[h] = 0.f; }
        for (int e = r0 + lane; e < r1; e += 64) {
            int s = adj[e];
#pragma unroll
            for (int h = 0; h < H; ++h) {
                float v = ssrc[s * H + h] + sd[h];
                v = v > 0.f ? v : 0.2f * v;
                float mn = fmaxf(m[h], v);
                l[h] = l[h] * __expf(m[h] - mn) + __expf(v - mn);
                m[h] = mn;
            }
        }
#pragma unroll
        for (int off = 32; off; off >>= 1)
#pragma unroll
            for (int h = 0; h < H; ++h) {
                float mo = __shfl_xor(m[h], off, 64);
                float lo = __shfl_xor(l[h], off, 64);
                float mn = fmaxf(m[h], mo);
                l[h] = l[h] * __expf(m[h] - mn) + lo * __expf(mo - mn);
                m[h] = mn;
            }
        float mh = m[hA], invl = 1.f / l[hA], sdh = sd[hA];
        for (int e = r0; e < r1; ++e) {
            int s = adj[e];
            float v = ssrc[s * H + hA] + sdh;
            v = v > 0.f ? v : 0.2f * v;
            float alpha = __expf(v - mh) * invl;
            const unsigned* hp = hb + (size_t)s * (HC / 2) + lane * UPL;
            if constexpr (UPL == 2) {
                uint2 u = *reinterpret_cast<const uint2*>(hp);
                acc[0] += alpha * bflo(u.x); acc[1] += alpha * bfhi(u.x);
                acc[2] += alpha * bflo(u.y); acc[3] += alpha * bfhi(u.y);
            } else {
                unsigned u = *hp;
                acc[0] += alpha * bflo(u); acc[1] += alpha * bfhi(u);
            }
        }
    }

#pragma unroll
    for (int f = 0; f < FPL; ++f) {
        float v = acc[f] + bias[lane * FPL + f];
        if (ELU) v = v > 0.f ? v : (__expf(v) - 1.f);
        acc[f] = v;
    }
    if constexpr (OUT_BF16) {
        unsigned* op = (unsigned*)outp + (size_t)n * (HC / 2) + lane * UPL;
        if constexpr (UPL == 2) {
            uint2 u = {packbf(acc[0], acc[1]), packbf(acc[2], acc[3])};
            *reinterpret_cast<uint2*>(op) = u;
        } else {
            *op = packbf(acc[0], acc[1]);
        }
    } else {
        float* op = (float*)outp + (size_t)n * HC + lane * FPL;
        if constexpr (FPL == 2) {
            *reinterpret_cast<float2*>(op) = make_float2(acc[0], acc[1]);
        } else {
#pragma unroll
            for (int f = 0; f < FPL; ++f) op[f] = acc[f];
        }
    }
}

// ---------- launch ----------
extern "C" void kernel_launch(void* const* d_in, const int* in_sizes, int n_in,
                              void* d_out, int out_size, void* d_ws, size_t ws_size,
                              hipStream_t stream) {
    const float* x   = (const float*)d_in[0];
    const int*   ei  = (const int*)d_in[1];
    const float* W1  = (const float*)d_in[2];
    const float* as1 = (const float*)d_in[3];
    const float* ad1 = (const float*)d_in[4];
    const float* b1  = (const float*)d_in[5];
    const float* W2  = (const float*)d_in[6];
    const float* as2 = (const float*)d_in[7];
    const float* ad2 = (const float*)d_in[8];
    const float* b2  = (const float*)d_in[9];
    float* out = (float*)d_out;

    const int N  = in_sizes[0] / 128;   // 50000
    const int E  = in_sizes[1] / 2;     // 800000
    const int ET = E + N;
    const int* src = ei;
    const int* dst = ei + E;

    // workspace (4B units)
    unsigned* ws = (unsigned*)d_ws;
    unsigned* xb    = ws;                              // N*64  (x bf16)
    unsigned* h1b   = xb    + (size_t)N * 64;          // N*128
    unsigned* agg1b = h1b   + (size_t)N * 128;         // N*128
    unsigned* h2b   = agg1b + (size_t)N * 128;         // N*64
    unsigned* Wt1   = h2b   + (size_t)N * 64;          // 16384
    unsigned* Wt2   = Wt1   + 16384;                   // 16384
    float*    ssrc1 = (float*)(Wt2 + 16384);           // N*4
    float*    sdst1 = ssrc1 + (size_t)N * 4;           // N*4
    float*    ssrc2 = sdst1 + (size_t)N * 4;           // N
    float*    sdst2 = ssrc2 + N;                       // N
    int*      deg   = (int*)(sdst2 + N);               // N (reused as cursor)
    int*      rowst = deg + N;                         // N+1
    int*      bsums = rowst + N + 1;                   // 64
    int*      adj   = bsums + 64;                      // ET

    const int B = 256;
    auto blocks = [](size_t n, int b) { return (int)((n + b - 1) / b); };
    const int nscan = (N + SCAN_ELEMS - 1) / SCAN_ELEMS;

    // ---- converts ----
    cvt_pack_k<<<blocks((size_t)N * 64, B), B, 0, stream>>>(x, xb, (size_t)N * 64);
    wcvt_k<128, 256><<<blocks(128 * 256, B), B, 0, stream>>>(W1, (unsigned short*)Wt1);
    wcvt_k<256, 128><<<blocks(256 * 128, B), B, 0, stream>>>(W2, (unsigned short*)Wt2);

    // ---- CSR build ----
    fill_i32_k<<<blocks(N, B), B, 0, stream>>>(deg, N, 1);
    count_k<<<blocks(E, B), B, 0, stream>>>(dst, E, deg);
    scan1_k<<<nscan, SCAN_BLK, 0, stream>>>(deg, rowst, bsums, N);
    scan2_k<<<1, 64, 0, stream>>>(bsums, nscan);
    scan3_k<<<blocks(N + 1, B), B, 0, stream>>>(rowst, bsums, N, ET);
    initadj_k<<<blocks(N, B), B, 0, stream>>>(rowst, adj, deg, N);
    scatter_k<<<blocks(E, B), B, 0, stream>>>(src, dst, E, deg, adj);

    // ---- layer 1 ----
    {
        dim3 g((N + 127) / 128, 256 / 64);
        gemm_mfma_k<128, 256><<<g, 256, 0, stream>>>(xb, (const unsigned*)Wt1, (unsigned short*)h1b, N);
    }
    score_b_k<4, 64><<<blocks((size_t)N * 4, B), B, 0, stream>>>(h1b, as1, ad1, ssrc1, sdst1, N);
    node_agg_k<4, 64, true, true><<<(N + 3) / 4, 256, 0, stream>>>(rowst, adj, ssrc1, sdst1, h1b, b1, agg1b, N);

    // ---- layer 2 ----
    {
        dim3 g((N + 127) / 128, 128 / 64);
        gemm_mfma_k<256, 128><<<g, 256, 0, stream>>>(agg1b, (const unsigned*)Wt2, (unsigned short*)h2b, N);
    }
    score_b_k<1, 128><<<blocks(N, B), B, 0, stream>>>(h2b, as2, ad2, ssrc2, sdst2, N);
    node_agg_k<1, 128, false, false><<<(N + 3) / 4, 256, 0, stream>>>(rowst, adj, ssrc2, sdst2, h2b, b2, out, N);
}